// Round 1
// baseline (20613.904 us; speedup 1.0000x reference)
//
#include <hip/hip_runtime.h>
#include <hip/hip_cooperative_groups.h>

namespace cg = cooperative_groups;

#define Bb 32
#define Tt 512
#define Ee 512
#define Hh 1024

typedef __attribute__((ext_vector_type(8))) short bf16x8;
typedef __attribute__((ext_vector_type(4))) float f32x4;

__device__ __forceinline__ unsigned short f2bf(float f) {
  unsigned int u = __float_as_uint(f);
  u = (u + 0x7fffu + ((u >> 16) & 1u)) >> 16;
  return (unsigned short)u;
}
__device__ __forceinline__ float bf2f(unsigned short s) {
  return __uint_as_float(((unsigned int)s) << 16);
}
__device__ __forceinline__ float sigmoidf_(float x) {
  x = fminf(fmaxf(x, -30.f), 30.f);
  return 1.f / (1.f + __expf(-x));
}
__device__ __forceinline__ float tanh_fast(float x) {
  float xx = fminf(fmaxf(x, -15.f), 15.f);
  float e = __expf(2.f * xx);
  return (e - 1.f) / (e + 1.f);
}

// K1: gather embedding rows, write bf16 hi/lo pair; also zero h broadcast buf 0.
__global__ void gather_kernel(const int* __restrict__ x,
                              const float* __restrict__ emb,
                              unsigned short* __restrict__ emb_hi,
                              unsigned short* __restrict__ emb_lo,
                              unsigned short* __restrict__ hbuf) {
  long long gid = (long long)blockIdx.x * blockDim.x + threadIdx.x;
  long long stride = (long long)gridDim.x * blockDim.x;
  // zero hbuf[0] (hi+lo): 65536 ushorts = 16384 ushort4
  for (long long i = gid; i < 16384; i += stride)
    ((ushort4*)hbuf)[i] = make_ushort4(0, 0, 0, 0);
  long long n4 = (long long)Bb * Tt * Ee / 4;  // float4 granules
  for (long long i = gid; i < n4; i += stride) {
    long long bt = i >> 7;       // Ee/4 = 128
    int e4 = (int)(i & 127);
    int row = x[bt];
    row = min(max(row, 0), 31999);   // defensive clamp
    float4 v = ((const float4*)(emb + (long long)row * Ee))[e4];
    ushort4 hv, lv;
    hv.x = f2bf(v.x); lv.x = f2bf(v.x - bf2f(hv.x));
    hv.y = f2bf(v.y); lv.y = f2bf(v.y - bf2f(hv.y));
    hv.z = f2bf(v.z); lv.z = f2bf(v.z - bf2f(hv.z));
    hv.w = f2bf(v.w); lv.w = f2bf(v.w - bf2f(hv.w));
    ((ushort4*)emb_hi)[i] = hv;
    ((ushort4*)emb_lo)[i] = lv;
  }
}

// K2: persistent cooperative LSTM. 256 WGs; WG wg owns hidden units [wg*4, wg*4+4).
// Gate-slice cols c=0..15: gate g=c>>2 (i,f,g,o), unit offset du=c&3;
// global weight row = g*1024 + wg*4 + du.
__global__ __launch_bounds__(256, 1)
void lstm_kernel(const unsigned short* __restrict__ emb_hi,
                 const unsigned short* __restrict__ emb_lo,
                 unsigned short* __restrict__ hbuf,
                 const float* __restrict__ W_ih,
                 const float* __restrict__ W_hh,
                 const float* __restrict__ b_ih,
                 const float* __restrict__ b_hh,
                 float* __restrict__ out) {
  __shared__ unsigned short sWih_hi[16 * 512];
  __shared__ unsigned short sWih_lo[16 * 512];
  __shared__ unsigned short sWhh_hi[16 * 1024];
  __shared__ unsigned short sWhh_lo[16 * 1024];
  __shared__ float sAcc[4][2][16][16];
  __shared__ float sBias[16];
  __shared__ float sC[32][4];

  const int tid = threadIdx.x;
  const int lane = tid & 63;
  const int wv = tid >> 6;
  const int wg = blockIdx.x;
  const int j0 = wg * 4;

  // ---- stage W_ih slice (16 rows x 512) as hi/lo bf16, XOR-swizzled ----
  for (int idx = tid; idx < 16 * 64; idx += 256) {
    int c = idx >> 6, kc8 = idx & 63;
    int grow = (c >> 2) * Hh + j0 + (c & 3);
    const float* src = W_ih + (long long)grow * Ee + kc8 * 8;
    int us = (c * 512 + kc8 * 8) ^ ((c & 7) << 3);
#pragma unroll
    for (int j = 0; j < 8; j++) {
      float f = src[j];
      unsigned short h = f2bf(f);
      sWih_hi[us + j] = h;
      sWih_lo[us + j] = f2bf(f - bf2f(h));
    }
  }
  // ---- stage W_hh slice (16 rows x 1024) ----
  for (int idx = tid; idx < 16 * 128; idx += 256) {
    int c = idx >> 7, kc8 = idx & 127;
    int grow = (c >> 2) * Hh + j0 + (c & 3);
    const float* src = W_hh + (long long)grow * Hh + kc8 * 8;
    int us = (c * 1024 + kc8 * 8) ^ ((c & 7) << 3);
#pragma unroll
    for (int j = 0; j < 8; j++) {
      float f = src[j];
      unsigned short h = f2bf(f);
      sWhh_hi[us + j] = h;
      sWhh_lo[us + j] = f2bf(f - bf2f(h));
    }
  }
  if (tid < 16) {
    int grow = (tid >> 2) * Hh + j0 + (tid & 3);
    sBias[tid] = b_ih[grow] + b_hh[grow];
  }
  if (tid < 128) sC[tid & 31][tid >> 5] = 0.f;
  __syncthreads();

  const int r16 = lane & 15;          // A-frag row within 16-tile (batch)
  const int kg = (lane >> 4) * 8;     // k-offset within 32-chunk
  const int col = lane & 15;          // B-frag col = gate-slice row
  const int xr = (col & 7) << 3;      // LDS swizzle

  cg::grid_group grid = cg::this_grid();

  float h_last = 0.f, c_last = 0.f;

  for (int t = 0; t < Tt; t++) {
    f32x4 acc[2][3];
#pragma unroll
    for (int mt = 0; mt < 2; mt++)
#pragma unroll
      for (int cb = 0; cb < 3; cb++)
        acc[mt][cb] = (f32x4){0.f, 0.f, 0.f, 0.f};

    // ---- x_proj contribution: K=512 -> 16 k-chunks, wave wv takes wv+4q ----
#pragma unroll
    for (int q = 0; q < 4; q++) {
      int kc = wv + q * 4;
      int bo = (col * 512 + kc * 32 + kg) ^ xr;
      bf16x8 bH = *(const bf16x8*)(sWih_hi + bo);
      bf16x8 bL = *(const bf16x8*)(sWih_lo + bo);
#pragma unroll
      for (int mt = 0; mt < 2; mt++) {
        int rb = mt * 16 + r16;
        int ai = (rb * Tt + t) * Ee + kc * 32 + kg;
        bf16x8 aH = *(const bf16x8*)(emb_hi + ai);
        bf16x8 aL = *(const bf16x8*)(emb_lo + ai);
        acc[mt][0] = __builtin_amdgcn_mfma_f32_16x16x32_bf16(aH, bH, acc[mt][0], 0, 0, 0);
        acc[mt][1] = __builtin_amdgcn_mfma_f32_16x16x32_bf16(aH, bL, acc[mt][1], 0, 0, 0);
        acc[mt][2] = __builtin_amdgcn_mfma_f32_16x16x32_bf16(aL, bH, acc[mt][2], 0, 0, 0);
      }
    }
    // ---- recurrent contribution: K=1024 -> 32 k-chunks ----
    const unsigned short* hb = hbuf + (t & 1) * 65536;
#pragma unroll
    for (int q = 0; q < 8; q++) {
      int kc = wv + q * 4;
      int bo = (col * 1024 + kc * 32 + kg) ^ xr;
      bf16x8 bH = *(const bf16x8*)(sWhh_hi + bo);
      bf16x8 bL = *(const bf16x8*)(sWhh_lo + bo);
#pragma unroll
      for (int mt = 0; mt < 2; mt++) {
        int rb = mt * 16 + r16;
        int ai = rb * Hh + kc * 32 + kg;
        bf16x8 aH = *(const bf16x8*)(hb + ai);
        bf16x8 aL = *(const bf16x8*)(hb + 32768 + ai);
        acc[mt][0] = __builtin_amdgcn_mfma_f32_16x16x32_bf16(aH, bH, acc[mt][0], 0, 0, 0);
        acc[mt][1] = __builtin_amdgcn_mfma_f32_16x16x32_bf16(aH, bL, acc[mt][1], 0, 0, 0);
        acc[mt][2] = __builtin_amdgcn_mfma_f32_16x16x32_bf16(aL, bH, acc[mt][2], 0, 0, 0);
      }
    }

    // cross-wave K-split reduction via LDS
#pragma unroll
    for (int mt = 0; mt < 2; mt++) {
      f32x4 tot = acc[mt][0] + acc[mt][1] + acc[mt][2];
#pragma unroll
      for (int r = 0; r < 4; r++)
        sAcc[wv][mt][(lane >> 4) * 4 + r][col] = tot[r];
    }
    __syncthreads();

    if (tid < 128) {
      int b = tid & 31, du = tid >> 5;
      int mt = b >> 4, rr = b & 15;
      float g0 = sBias[0 * 4 + du], g1 = sBias[1 * 4 + du];
      float g2 = sBias[2 * 4 + du], g3 = sBias[3 * 4 + du];
#pragma unroll
      for (int w = 0; w < 4; w++) {
        g0 += sAcc[w][mt][rr][0 * 4 + du];
        g1 += sAcc[w][mt][rr][1 * 4 + du];
        g2 += sAcc[w][mt][rr][2 * 4 + du];
        g3 += sAcc[w][mt][rr][3 * 4 + du];
      }
      float ig = sigmoidf_(g0);
      float fg = sigmoidf_(g1);
      float gg = tanh_fast(g2);
      float og = sigmoidf_(g3);
      float cn = fg * sC[b][du] + ig * gg;
      sC[b][du] = cn;
      float hn = og * tanh_fast(cn);
      h_last = hn; c_last = cn;
      int hj = j0 + du;
      out[((long long)b * Tt + t) * Hh + hj] = hn;
      unsigned short hh = f2bf(hn);
      unsigned short hl = f2bf(hn - bf2f(hh));
      unsigned short* nb = hbuf + ((t + 1) & 1) * 65536;
      nb[b * 1024 + hj] = hh;
      nb[32768 + b * 1024 + hj] = hl;
    }
    grid.sync();
  }

  if (tid < 128) {
    int b = tid & 31, du = tid >> 5;
    int hj = j0 + du;
    out[16777216LL + b * Hh + hj] = h_last;                 // state_h
    out[16777216LL + 32768 + b * Hh + hj] = c_last;         // state_c
  }
}

extern "C" void kernel_launch(void* const* d_in, const int* in_sizes, int n_in,
                              void* d_out, int out_size, void* d_ws, size_t ws_size,
                              hipStream_t stream) {
  const int* x      = (const int*)d_in[0];
  const float* emb  = (const float*)d_in[1];
  const float* W_ih = (const float*)d_in[2];
  const float* W_hh = (const float*)d_in[3];
  const float* b_ih = (const float*)d_in[4];
  const float* b_hh = (const float*)d_in[5];
  float* out = (float*)d_out;

  unsigned short* emb_hi = (unsigned short*)d_ws;      // 16 MB
  unsigned short* emb_lo = emb_hi + 8388608;           // 16 MB
  unsigned short* hbuf   = emb_lo + 8388608;           // [2][hi/lo][32][1024] = 256 KB

  hipLaunchKernelGGL(gather_kernel, dim3(2048), dim3(256), 0, stream,
                     x, emb, emb_hi, emb_lo, hbuf);

  void* args[] = { (void*)&emb_hi, (void*)&emb_lo, (void*)&hbuf,
                   (void*)&W_ih, (void*)&W_hh, (void*)&b_ih, (void*)&b_hh,
                   (void*)&out };
  hipLaunchCooperativeKernel((void*)lstm_kernel, dim3(256), dim3(256), args, 0, stream);
}

// Round 2
// 11831.858 us; speedup vs baseline: 1.7422x; 1.7422x over previous
//
#include <hip/hip_runtime.h>

#define Bb 32
#define Tt 512
#define Ee 512
#define Hh 1024

typedef __attribute__((ext_vector_type(8))) short bf16x8;
typedef __attribute__((ext_vector_type(4))) float f32x4;

__device__ __forceinline__ unsigned short f2bf(float f) {
  unsigned int u = __float_as_uint(f);
  u = (u + 0x7fffu + ((u >> 16) & 1u)) >> 16;
  return (unsigned short)u;
}
__device__ __forceinline__ float bf2f(unsigned short s) {
  return __uint_as_float(((unsigned int)s) << 16);
}
__device__ __forceinline__ float sigmoidf_(float x) {
  x = fminf(fmaxf(x, -30.f), 30.f);
  return 1.f / (1.f + __expf(-x));
}
__device__ __forceinline__ float tanh_fast(float x) {
  float xx = fminf(fmaxf(x, -15.f), 15.f);
  float e = __expf(2.f * xx);
  return (e - 1.f) / (e + 1.f);
}

// K1: gather embedding rows -> bf16 hi/lo; zero h buffer 0 and barrier state.
__global__ void gather_kernel(const int* __restrict__ x,
                              const float* __restrict__ emb,
                              unsigned short* __restrict__ emb_hi,
                              unsigned short* __restrict__ emb_lo,
                              unsigned short* __restrict__ hbuf,
                              unsigned* __restrict__ bar) {
  long long gid = (long long)blockIdx.x * blockDim.x + threadIdx.x;
  long long stride = (long long)gridDim.x * blockDim.x;
  for (long long i = gid; i < 16384; i += stride)
    ((ushort4*)hbuf)[i] = make_ushort4(0, 0, 0, 0);
  for (long long i = gid; i < 288; i += stride)
    bar[i] = 0u;
  long long n4 = (long long)Bb * Tt * Ee / 4;
  for (long long i = gid; i < n4; i += stride) {
    long long bt = i >> 7;
    int e4 = (int)(i & 127);
    int row = x[bt];
    row = min(max(row, 0), 31999);
    float4 v = ((const float4*)(emb + (long long)row * Ee))[e4];
    ushort4 hv, lv;
    hv.x = f2bf(v.x); lv.x = f2bf(v.x - bf2f(hv.x));
    hv.y = f2bf(v.y); lv.y = f2bf(v.y - bf2f(hv.y));
    hv.z = f2bf(v.z); lv.z = f2bf(v.z - bf2f(hv.z));
    hv.w = f2bf(v.w); lv.w = f2bf(v.w - bf2f(hv.w));
    ((ushort4*)emb_hi)[i] = hv;
    ((ushort4*)emb_lo)[i] = lv;
  }
}

// K2: persistent LSTM. 256 WGs; WG owns 4 hidden units j0..j0+3 with
// j0 = (wg&7)*128 + (wg>>3)*4  (XCD-local 64B output lines, bid%8 = XCD).
__global__ __launch_bounds__(256, 1)
void lstm_kernel(const unsigned short* __restrict__ emb_hi,
                 const unsigned short* __restrict__ emb_lo,
                 unsigned short* __restrict__ hbuf,
                 unsigned* __restrict__ bar,
                 const float* __restrict__ W_ih,
                 const float* __restrict__ W_hh,
                 const float* __restrict__ b_ih,
                 const float* __restrict__ b_hh,
                 float* __restrict__ out) {
  __shared__ unsigned short sWih_hi[16 * 512];
  __shared__ unsigned short sWih_lo[16 * 512];
  __shared__ unsigned short sWhh_hi[16 * 1024];
  __shared__ unsigned short sWhh_lo[16 * 1024];
  __shared__ float sAcc[4][2][16][16];
  __shared__ float sBias[16];
  __shared__ float sC[32][4];

  const int tid = threadIdx.x;
  const int lane = tid & 63;
  const int wv = tid >> 6;
  const int wg = blockIdx.x;
  const int j0 = (wg & 7) * 128 + (wg >> 3) * 4;

  // ---- stage W_ih slice (16 rows x 512) hi/lo bf16, XOR-swizzled ----
  for (int idx = tid; idx < 16 * 64; idx += 256) {
    int c = idx >> 6, kc8 = idx & 63;
    int grow = (c >> 2) * Hh + j0 + (c & 3);
    const float* src = W_ih + (long long)grow * Ee + kc8 * 8;
    int us = (c * 512 + kc8 * 8) ^ ((c & 7) << 3);
#pragma unroll
    for (int j = 0; j < 8; j++) {
      float f = src[j];
      unsigned short h = f2bf(f);
      sWih_hi[us + j] = h;
      sWih_lo[us + j] = f2bf(f - bf2f(h));
    }
  }
  // ---- stage W_hh slice (16 rows x 1024) ----
  for (int idx = tid; idx < 16 * 128; idx += 256) {
    int c = idx >> 7, kc8 = idx & 127;
    int grow = (c >> 2) * Hh + j0 + (c & 3);
    const float* src = W_hh + (long long)grow * Hh + kc8 * 8;
    int us = (c * 1024 + kc8 * 8) ^ ((c & 7) << 3);
#pragma unroll
    for (int j = 0; j < 8; j++) {
      float f = src[j];
      unsigned short h = f2bf(f);
      sWhh_hi[us + j] = h;
      sWhh_lo[us + j] = f2bf(f - bf2f(h));
    }
  }
  if (tid < 16) {
    int grow = (tid >> 2) * Hh + j0 + (tid & 3);
    sBias[tid] = b_ih[grow] + b_hh[grow];
  }
  if (tid < 128) sC[tid >> 2][tid & 3] = 0.f;
  __syncthreads();

  const int r16 = lane & 15;        // A-frag row (batch)
  const int kg = (lane >> 4) * 8;   // k-offset in 32-chunk
  const int col = lane & 15;        // B-frag col = gate-slice row
  const int xr = (col & 7) << 3;    // LDS swizzle

  const int grp = (wg >> 4) * 16;   // group counter index (64B padded)

  float h_last = 0.f, c_last = 0.f;

  for (int t = 0; t < Tt; t++) {
    f32x4 acc[2][3];
#pragma unroll
    for (int mt = 0; mt < 2; mt++)
#pragma unroll
      for (int cb = 0; cb < 3; cb++)
        acc[mt][cb] = (f32x4){0.f, 0.f, 0.f, 0.f};

    // ---- x_proj contribution (independent of h; overlaps barrier wait) ----
#pragma unroll
    for (int q = 0; q < 4; q++) {
      int kc = wv + q * 4;
      int bo = (col * 512 + kc * 32 + kg) ^ xr;
      bf16x8 bH = *(const bf16x8*)(sWih_hi + bo);
      bf16x8 bL = *(const bf16x8*)(sWih_lo + bo);
#pragma unroll
      for (int mt = 0; mt < 2; mt++) {
        int rb = mt * 16 + r16;
        int ai = (rb * Tt + t) * Ee + kc * 32 + kg;
        bf16x8 aH = *(const bf16x8*)(emb_hi + ai);
        bf16x8 aL = *(const bf16x8*)(emb_lo + ai);
        acc[mt][0] = __builtin_amdgcn_mfma_f32_16x16x32_bf16(aH, bH, acc[mt][0], 0, 0, 0);
        acc[mt][1] = __builtin_amdgcn_mfma_f32_16x16x32_bf16(aH, bL, acc[mt][1], 0, 0, 0);
        acc[mt][2] = __builtin_amdgcn_mfma_f32_16x16x32_bf16(aL, bH, acc[mt][2], 0, 0, 0);
      }
    }

    // ---- wait until h[t] is published (flag >= t) ----
    if (tid == 0) {
      while (__hip_atomic_load(bar + 272, __ATOMIC_ACQUIRE,
                               __HIP_MEMORY_SCOPE_AGENT) < (unsigned)t)
        __builtin_amdgcn_s_sleep(2);
    }
    __syncthreads();

    // ---- recurrent contribution: K=1024 -> 32 k-chunks ----
    const unsigned short* hb = hbuf + (t & 1) * 65536;
#pragma unroll
    for (int q = 0; q < 8; q++) {
      int kc = wv + q * 4;
      int bo = (col * 1024 + kc * 32 + kg) ^ xr;
      bf16x8 bH = *(const bf16x8*)(sWhh_hi + bo);
      bf16x8 bL = *(const bf16x8*)(sWhh_lo + bo);
#pragma unroll
      for (int mt = 0; mt < 2; mt++) {
        int rb = mt * 16 + r16;
        int ai = rb * Hh + kc * 32 + kg;
        bf16x8 aH = *(const bf16x8*)(hb + ai);
        bf16x8 aL = *(const bf16x8*)(hb + 32768 + ai);
        acc[mt][0] = __builtin_amdgcn_mfma_f32_16x16x32_bf16(aH, bH, acc[mt][0], 0, 0, 0);
        acc[mt][1] = __builtin_amdgcn_mfma_f32_16x16x32_bf16(aH, bL, acc[mt][1], 0, 0, 0);
        acc[mt][2] = __builtin_amdgcn_mfma_f32_16x16x32_bf16(aL, bH, acc[mt][2], 0, 0, 0);
      }
    }

    // ---- cross-wave K-split reduction via LDS ----
#pragma unroll
    for (int mt = 0; mt < 2; mt++) {
      f32x4 tot = acc[mt][0] + acc[mt][1] + acc[mt][2];
#pragma unroll
      for (int r = 0; r < 4; r++)
        sAcc[wv][mt][(lane >> 4) * 4 + r][col] = tot[r];
    }
    __syncthreads();

    if (tid < 128) {
      int b = tid >> 2, du = tid & 3;
      int mt = b >> 4, rr = b & 15;
      float g0 = sBias[0 * 4 + du], g1 = sBias[1 * 4 + du];
      float g2 = sBias[2 * 4 + du], g3 = sBias[3 * 4 + du];
#pragma unroll
      for (int w = 0; w < 4; w++) {
        g0 += sAcc[w][mt][rr][0 * 4 + du];
        g1 += sAcc[w][mt][rr][1 * 4 + du];
        g2 += sAcc[w][mt][rr][2 * 4 + du];
        g3 += sAcc[w][mt][rr][3 * 4 + du];
      }
      float ig = sigmoidf_(g0);
      float fg = sigmoidf_(g1);
      float gg = tanh_fast(g2);
      float og = sigmoidf_(g3);
      float cn = fg * sC[b][du] + ig * gg;
      sC[b][du] = cn;
      float hn = og * tanh_fast(cn);
      h_last = hn; c_last = cn;
      int hj = j0 + du;
      out[((long long)b * Tt + t) * Hh + hj] = hn;
      unsigned short hh = f2bf(hn);
      unsigned short hl = f2bf(hn - bf2f(hh));
      unsigned short* nb = hbuf + ((t + 1) & 1) * 65536;
      nb[b * 1024 + hj] = hh;
      nb[32768 + b * 1024 + hj] = hl;
    }
    __syncthreads();   // all h stores drained to L2 (vmcnt(0) per wave)

    // ---- arrive: 2-level monotonic barrier, publish flag = t+1 ----
    if (tid == 0) {
      __threadfence();  // write back L2 so other XCDs can see h
      unsigned old = __hip_atomic_fetch_add(bar + grp, 1u, __ATOMIC_ACQ_REL,
                                            __HIP_MEMORY_SCOPE_AGENT);
      if ((old & 15u) == 15u) {
        unsigned old2 = __hip_atomic_fetch_add(bar + 256, 1u, __ATOMIC_ACQ_REL,
                                               __HIP_MEMORY_SCOPE_AGENT);
        if ((old2 & 15u) == 15u) {
          __hip_atomic_store(bar + 272, (unsigned)(t + 1), __ATOMIC_RELEASE,
                             __HIP_MEMORY_SCOPE_AGENT);
        }
      }
    }
  }

  if (tid < 128) {
    int b = tid >> 2, du = tid & 3;
    int hj = j0 + du;
    out[16777216LL + b * Hh + hj] = h_last;           // state_h
    out[16777216LL + 32768 + b * Hh + hj] = c_last;   // state_c
  }
}

extern "C" void kernel_launch(void* const* d_in, const int* in_sizes, int n_in,
                              void* d_out, int out_size, void* d_ws, size_t ws_size,
                              hipStream_t stream) {
  const int* x      = (const int*)d_in[0];
  const float* emb  = (const float*)d_in[1];
  const float* W_ih = (const float*)d_in[2];
  const float* W_hh = (const float*)d_in[3];
  const float* b_ih = (const float*)d_in[4];
  const float* b_hh = (const float*)d_in[5];
  float* out = (float*)d_out;

  unsigned short* emb_hi = (unsigned short*)d_ws;      // 16 MB
  unsigned short* emb_lo = emb_hi + 8388608;           // 16 MB
  unsigned short* hbuf   = emb_lo + 8388608;           // 2 x (hi+lo) x 32 x 1024 = 256 KB
  unsigned*       bar    = (unsigned*)(hbuf + 131072); // barrier state (1152 B)

  hipLaunchKernelGGL(gather_kernel, dim3(2048), dim3(256), 0, stream,
                     x, emb, emb_hi, emb_lo, hbuf, bar);

  void* args[] = { (void*)&emb_hi, (void*)&emb_lo, (void*)&hbuf, (void*)&bar,
                   (void*)&W_ih, (void*)&W_hh, (void*)&b_ih, (void*)&b_hh,
                   (void*)&out };
  hipLaunchCooperativeKernel((void*)lstm_kernel, dim3(256), dim3(256), args, 0, stream);
}

// Round 3
// 8321.130 us; speedup vs baseline: 2.4773x; 1.4219x over previous
//
#include <hip/hip_runtime.h>

#define Bb 32
#define Tt 512
#define Ee 512
#define Hh 1024

typedef __attribute__((ext_vector_type(8))) short bf16x8;
typedef __attribute__((ext_vector_type(4))) float f32x4;

__device__ __forceinline__ unsigned short f2bf(float f) {
  unsigned int u = __float_as_uint(f);
  u = (u + 0x7fffu + ((u >> 16) & 1u)) >> 16;
  return (unsigned short)u;
}
__device__ __forceinline__ float bf2f(unsigned short s) {
  return __uint_as_float(((unsigned int)s) << 16);
}
__device__ __forceinline__ float sigmoidf_(float x) {
  x = fminf(fmaxf(x, -30.f), 30.f);
  return 1.f / (1.f + __expf(-x));
}
__device__ __forceinline__ float tanh_fast(float x) {
  float xx = fminf(fmaxf(x, -15.f), 15.f);
  float e = __expf(2.f * xx);
  return (e - 1.f) / (e + 1.f);
}

// K1: gather embedding rows -> bf16 hi/lo; zero h buffer 0 and barrier state.
__global__ void gather_kernel(const int* __restrict__ x,
                              const float* __restrict__ emb,
                              unsigned short* __restrict__ emb_hi,
                              unsigned short* __restrict__ emb_lo,
                              unsigned short* __restrict__ hbuf,
                              unsigned* __restrict__ bar) {
  long long gid = (long long)blockIdx.x * blockDim.x + threadIdx.x;
  long long stride = (long long)gridDim.x * blockDim.x;
  for (long long i = gid; i < 16384; i += stride)
    ((ushort4*)hbuf)[i] = make_ushort4(0, 0, 0, 0);
  for (long long i = gid; i < 288; i += stride)
    bar[i] = 0u;
  long long n4 = (long long)Bb * Tt * Ee / 4;
  for (long long i = gid; i < n4; i += stride) {
    long long bt = i >> 7;
    int e4 = (int)(i & 127);
    int row = x[bt];
    row = min(max(row, 0), 31999);
    float4 v = ((const float4*)(emb + (long long)row * Ee))[e4];
    ushort4 hv, lv;
    hv.x = f2bf(v.x); lv.x = f2bf(v.x - bf2f(hv.x));
    hv.y = f2bf(v.y); lv.y = f2bf(v.y - bf2f(hv.y));
    hv.z = f2bf(v.z); lv.z = f2bf(v.z - bf2f(hv.z));
    hv.w = f2bf(v.w); lv.w = f2bf(v.w - bf2f(hv.w));
    ((ushort4*)emb_hi)[i] = hv;
    ((ushort4*)emb_lo)[i] = lv;
  }
}

// K2: persistent LSTM. 256 WGs; WG owns 4 hidden units j0..j0+3 with
// j0 = (wg&7)*128 + (wg>>3)*4  (XCD-local 64B output lines, bid%8 = XCD).
// Cross-WG data (hbuf, barrier) moves ONLY via device-scope (sc1/LLC) ops:
// no buffer_wbl2 anywhere, one buffer_inv per wave per step.
__global__ __launch_bounds__(256, 1)
void lstm_kernel(const unsigned short* __restrict__ emb_hi,
                 const unsigned short* __restrict__ emb_lo,
                 unsigned short* __restrict__ hbuf,
                 unsigned* __restrict__ bar,
                 const float* __restrict__ W_ih,
                 const float* __restrict__ W_hh,
                 const float* __restrict__ b_ih,
                 const float* __restrict__ b_hh,
                 float* __restrict__ out) {
  __shared__ unsigned short sWih_hi[16 * 512];
  __shared__ unsigned short sWih_lo[16 * 512];
  __shared__ unsigned short sWhh_hi[16 * 1024];
  __shared__ unsigned short sWhh_lo[16 * 1024];
  __shared__ float sAcc[4][2][16][17];   // padded: no 4/8-way bank conflict
  __shared__ float sBias[16];
  __shared__ float sC[32][4];

  const int tid = threadIdx.x;
  const int lane = tid & 63;
  const int wv = tid >> 6;
  const int wg = blockIdx.x;
  const int j0 = (wg & 7) * 128 + (wg >> 3) * 4;

  // ---- stage W_ih slice (16 rows x 512) hi/lo bf16, XOR-swizzled ----
  for (int idx = tid; idx < 16 * 64; idx += 256) {
    int c = idx >> 6, kc8 = idx & 63;
    int grow = (c >> 2) * Hh + j0 + (c & 3);
    const float* src = W_ih + (long long)grow * Ee + kc8 * 8;
    int us = (c * 512 + kc8 * 8) ^ ((c & 7) << 3);
#pragma unroll
    for (int j = 0; j < 8; j++) {
      float f = src[j];
      unsigned short h = f2bf(f);
      sWih_hi[us + j] = h;
      sWih_lo[us + j] = f2bf(f - bf2f(h));
    }
  }
  // ---- stage W_hh slice (16 rows x 1024) ----
  for (int idx = tid; idx < 16 * 128; idx += 256) {
    int c = idx >> 7, kc8 = idx & 127;
    int grow = (c >> 2) * Hh + j0 + (c & 3);
    const float* src = W_hh + (long long)grow * Hh + kc8 * 8;
    int us = (c * 1024 + kc8 * 8) ^ ((c & 7) << 3);
#pragma unroll
    for (int j = 0; j < 8; j++) {
      float f = src[j];
      unsigned short h = f2bf(f);
      sWhh_hi[us + j] = h;
      sWhh_lo[us + j] = f2bf(f - bf2f(h));
    }
  }
  if (tid < 16) {
    int grow = (tid >> 2) * Hh + j0 + (tid & 3);
    sBias[tid] = b_ih[grow] + b_hh[grow];
  }
  if (tid < 128) sC[tid >> 2][tid & 3] = 0.f;
  __syncthreads();

  const int r16 = lane & 15;        // A-frag row (batch)
  const int kg = (lane >> 4) * 8;   // k-offset in 32-chunk
  const int col = lane & 15;        // B-frag col = gate-slice row
  const int xr = (col & 7) << 3;    // LDS swizzle

  const int grp = (wg >> 4) * 16;   // group counter (64B-padded stride)

  float h_last = 0.f, c_last = 0.f;

  for (int t = 0; t < Tt; t++) {
    f32x4 acc[2][3];
#pragma unroll
    for (int mt = 0; mt < 2; mt++)
#pragma unroll
      for (int cb = 0; cb < 3; cb++)
        acc[mt][cb] = (f32x4){0.f, 0.f, 0.f, 0.f};

    // ---- x_proj contribution (independent of h; overlaps barrier wait) ----
#pragma unroll
    for (int q = 0; q < 4; q++) {
      int kc = wv + q * 4;
      int bo = (col * 512 + kc * 32 + kg) ^ xr;
      bf16x8 bH = *(const bf16x8*)(sWih_hi + bo);
      bf16x8 bL = *(const bf16x8*)(sWih_lo + bo);
#pragma unroll
      for (int mt = 0; mt < 2; mt++) {
        int rb = mt * 16 + r16;
        int ai = (rb * Tt + t) * Ee + kc * 32 + kg;
        bf16x8 aH = *(const bf16x8*)(emb_hi + ai);
        bf16x8 aL = *(const bf16x8*)(emb_lo + ai);
        acc[mt][0] = __builtin_amdgcn_mfma_f32_16x16x32_bf16(aH, bH, acc[mt][0], 0, 0, 0);
        acc[mt][1] = __builtin_amdgcn_mfma_f32_16x16x32_bf16(aH, bL, acc[mt][1], 0, 0, 0);
        acc[mt][2] = __builtin_amdgcn_mfma_f32_16x16x32_bf16(aL, bH, acc[mt][2], 0, 0, 0);
      }
    }

    // ---- wait until h[t] is published: relaxed LLC spin, then ONE acquire ----
    if (tid == 0) {
      while (__hip_atomic_load(bar + 272, __ATOMIC_RELAXED,
                               __HIP_MEMORY_SCOPE_AGENT) < (unsigned)t)
        __builtin_amdgcn_s_sleep(1);
    }
    __syncthreads();
    __builtin_amdgcn_fence(__ATOMIC_ACQUIRE, "agent");  // one buffer_inv/wave

    // ---- recurrent contribution: K=1024 -> 32 k-chunks ----
    const unsigned short* hb = hbuf + (t & 1) * 65536;
#pragma unroll
    for (int q = 0; q < 8; q++) {
      int kc = wv + q * 4;
      int bo = (col * 1024 + kc * 32 + kg) ^ xr;
      bf16x8 bH = *(const bf16x8*)(sWhh_hi + bo);
      bf16x8 bL = *(const bf16x8*)(sWhh_lo + bo);
#pragma unroll
      for (int mt = 0; mt < 2; mt++) {
        int rb = mt * 16 + r16;
        int ai = rb * Hh + kc * 32 + kg;
        bf16x8 aH = *(const bf16x8*)(hb + ai);
        bf16x8 aL = *(const bf16x8*)(hb + 32768 + ai);
        acc[mt][0] = __builtin_amdgcn_mfma_f32_16x16x32_bf16(aH, bH, acc[mt][0], 0, 0, 0);
        acc[mt][1] = __builtin_amdgcn_mfma_f32_16x16x32_bf16(aH, bL, acc[mt][1], 0, 0, 0);
        acc[mt][2] = __builtin_amdgcn_mfma_f32_16x16x32_bf16(aL, bH, acc[mt][2], 0, 0, 0);
      }
    }

    // ---- cross-wave K-split reduction via LDS ----
#pragma unroll
    for (int mt = 0; mt < 2; mt++) {
      f32x4 tot = acc[mt][0] + acc[mt][1] + acc[mt][2];
#pragma unroll
      for (int r = 0; r < 4; r++)
        sAcc[wv][mt][(lane >> 4) * 4 + r][col] = tot[r];
    }
    __syncthreads();

    if (tid < 128) {
      int b = tid >> 2, du = tid & 3;
      int mt = b >> 4, rr = b & 15;
      float g0 = sBias[0 * 4 + du], g1 = sBias[1 * 4 + du];
      float g2 = sBias[2 * 4 + du], g3 = sBias[3 * 4 + du];
#pragma unroll
      for (int w = 0; w < 4; w++) {
        g0 += sAcc[w][mt][rr][0 * 4 + du];
        g1 += sAcc[w][mt][rr][1 * 4 + du];
        g2 += sAcc[w][mt][rr][2 * 4 + du];
        g3 += sAcc[w][mt][rr][3 * 4 + du];
      }
      float ig = sigmoidf_(g0);
      float fg = sigmoidf_(g1);
      float gg = tanh_fast(g2);
      float og = sigmoidf_(g3);
      float cn = fg * sC[b][du] + ig * gg;
      sC[b][du] = cn;
      float hn = og * tanh_fast(cn);
      h_last = hn; c_last = cn;
      int hj = j0 + du;
      out[((long long)b * Tt + t) * Hh + hj] = hn;   // plain (harness-only reader)

      // h broadcast: device-scope (LLC) u32 stores, hi/lo pairs via shfl
      unsigned short hh = f2bf(hn);
      unsigned short hl = f2bf(hn - bf2f(hh));
      unsigned pack = ((unsigned)hl << 16) | (unsigned)hh;
      unsigned other = __shfl_xor(pack, 1, 64);
      unsigned* nb32 = (unsigned*)(hbuf + ((t + 1) & 1) * 65536);
      int base = b * 1024 + j0;
      if ((du & 1) == 0) {
        unsigned w = (pack & 0xffffu) | ((other & 0xffffu) << 16);
        __hip_atomic_store(nb32 + ((base + du) >> 1), w,
                           __ATOMIC_RELAXED, __HIP_MEMORY_SCOPE_AGENT);
      } else {
        unsigned w = (other >> 16) | (pack & 0xffff0000u);
        __hip_atomic_store(nb32 + 16384 + ((base + du - 1) >> 1), w,
                           __ATOMIC_RELAXED, __HIP_MEMORY_SCOPE_AGENT);
      }
    }
    __syncthreads();   // per-wave vmcnt(0): sc1 stores globally visible

    // ---- arrive: 2-level monotonic barrier, all relaxed LLC atomics ----
    if (tid == 0) {
      unsigned old = __hip_atomic_fetch_add(bar + grp, 1u, __ATOMIC_RELAXED,
                                            __HIP_MEMORY_SCOPE_AGENT);
      if ((old & 15u) == 15u) {
        unsigned old2 = __hip_atomic_fetch_add(bar + 256, 1u, __ATOMIC_RELAXED,
                                               __HIP_MEMORY_SCOPE_AGENT);
        if ((old2 & 15u) == 15u) {
          __hip_atomic_store(bar + 272, (unsigned)(t + 1), __ATOMIC_RELAXED,
                             __HIP_MEMORY_SCOPE_AGENT);
        }
      }
    }
  }

  if (tid < 128) {
    int b = tid >> 2, du = tid & 3;
    int hj = j0 + du;
    out[16777216LL + b * Hh + hj] = h_last;           // state_h
    out[16777216LL + 32768 + b * Hh + hj] = c_last;   // state_c
  }
}

extern "C" void kernel_launch(void* const* d_in, const int* in_sizes, int n_in,
                              void* d_out, int out_size, void* d_ws, size_t ws_size,
                              hipStream_t stream) {
  const int* x      = (const int*)d_in[0];
  const float* emb  = (const float*)d_in[1];
  const float* W_ih = (const float*)d_in[2];
  const float* W_hh = (const float*)d_in[3];
  const float* b_ih = (const float*)d_in[4];
  const float* b_hh = (const float*)d_in[5];
  float* out = (float*)d_out;

  unsigned short* emb_hi = (unsigned short*)d_ws;      // 16 MB
  unsigned short* emb_lo = emb_hi + 8388608;           // 16 MB
  unsigned short* hbuf   = emb_lo + 8388608;           // 2 x (hi+lo) x 32 x 1024 = 256 KB
  unsigned*       bar    = (unsigned*)(hbuf + 131072); // barrier state (1152 B)

  hipLaunchKernelGGL(gather_kernel, dim3(2048), dim3(256), 0, stream,
                     x, emb, emb_hi, emb_lo, hbuf, bar);

  void* args[] = { (void*)&emb_hi, (void*)&emb_lo, (void*)&hbuf, (void*)&bar,
                   (void*)&W_ih, (void*)&W_hh, (void*)&b_ih, (void*)&b_hh,
                   (void*)&out };
  hipLaunchCooperativeKernel((void*)lstm_kernel, dim3(256), dim3(256), args, 0, stream);
}

// Round 4
// 6004.974 us; speedup vs baseline: 3.4328x; 1.3857x over previous
//
#include <hip/hip_runtime.h>

#define Bb 32
#define Tt 512
#define Ee 512
#define Hh 1024

typedef __attribute__((ext_vector_type(8))) short bf16x8;
typedef __attribute__((ext_vector_type(4))) float f32x4;
typedef unsigned long long u64;

__device__ __forceinline__ unsigned short f2bf(float f) {
  unsigned int u = __float_as_uint(f);
  u = (u + 0x7fffu + ((u >> 16) & 1u)) >> 16;
  return (unsigned short)u;
}
__device__ __forceinline__ float bf2f(unsigned short s) {
  return __uint_as_float(((unsigned int)s) << 16);
}
__device__ __forceinline__ float sigmoidf_(float x) {
  x = fminf(fmaxf(x, -30.f), 30.f);
  return 1.f / (1.f + __expf(-x));
}
__device__ __forceinline__ float tanh_fast(float x) {
  float xx = fminf(fmaxf(x, -15.f), 15.f);
  float e = __expf(2.f * xx);
  return (e - 1.f) / (e + 1.f);
}

// Device-scope (LLC) 16B read as two relaxed u64 atomic loads: bypasses
// stale L1/L2 — no buffer_inv/fence needed anywhere in the step loop.
__device__ __forceinline__ bf16x8 llc_load16(const unsigned short* p) {
  union { u64 q[2]; bf16x8 v; } u;
  const u64* p64 = (const u64*)p;
  u.q[0] = __hip_atomic_load(p64 + 0, __ATOMIC_RELAXED, __HIP_MEMORY_SCOPE_AGENT);
  u.q[1] = __hip_atomic_load(p64 + 1, __ATOMIC_RELAXED, __HIP_MEMORY_SCOPE_AGENT);
  return u.v;
}

// K1: gather embedding rows -> bf16 hi/lo; zero h buffer 0 and barrier state.
__global__ void gather_kernel(const int* __restrict__ x,
                              const float* __restrict__ emb,
                              unsigned short* __restrict__ emb_hi,
                              unsigned short* __restrict__ emb_lo,
                              unsigned short* __restrict__ hbuf,
                              unsigned* __restrict__ bar) {
  long long gid = (long long)blockIdx.x * blockDim.x + threadIdx.x;
  long long stride = (long long)gridDim.x * blockDim.x;
  for (long long i = gid; i < 16384; i += stride)
    ((ushort4*)hbuf)[i] = make_ushort4(0, 0, 0, 0);
  for (long long i = gid; i < 288; i += stride)
    bar[i] = 0u;
  long long n4 = (long long)Bb * Tt * Ee / 4;
  for (long long i = gid; i < n4; i += stride) {
    long long bt = i >> 7;
    int e4 = (int)(i & 127);
    int row = x[bt];
    row = min(max(row, 0), 31999);
    float4 v = ((const float4*)(emb + (long long)row * Ee))[e4];
    ushort4 hv, lv;
    hv.x = f2bf(v.x); lv.x = f2bf(v.x - bf2f(hv.x));
    hv.y = f2bf(v.y); lv.y = f2bf(v.y - bf2f(hv.y));
    hv.z = f2bf(v.z); lv.z = f2bf(v.z - bf2f(hv.z));
    hv.w = f2bf(v.w); lv.w = f2bf(v.w - bf2f(hv.w));
    ((ushort4*)emb_hi)[i] = hv;
    ((ushort4*)emb_lo)[i] = lv;
  }
}

// K2: persistent LSTM. 256 WGs; WG owns 4 hidden units j0..j0+3 with
// j0 = (wg&7)*128 + (wg>>3)*4  (XCD-local 64B output lines).
// All cross-WG traffic is device-scope (sc1/LLC): stores sc1, loads sc1,
// barrier relaxed atomics. ZERO fences / buffer_inv / buffer_wbl2 in loop.
__global__ __launch_bounds__(256, 1)
void lstm_kernel(const unsigned short* __restrict__ emb_hi,
                 const unsigned short* __restrict__ emb_lo,
                 unsigned short* __restrict__ hbuf,
                 unsigned* __restrict__ bar,
                 const float* __restrict__ W_ih,
                 const float* __restrict__ W_hh,
                 const float* __restrict__ b_ih,
                 const float* __restrict__ b_hh,
                 float* __restrict__ out) {
  __shared__ unsigned short sWih_hi[16 * 512];
  __shared__ unsigned short sWih_lo[16 * 512];
  __shared__ unsigned short sWhh_hi[16 * 1024];
  __shared__ unsigned short sWhh_lo[16 * 1024];
  __shared__ float sAcc[4][2][16][17];
  __shared__ float sBias[16];
  __shared__ float sC[32][4];

  const int tid = threadIdx.x;
  const int lane = tid & 63;
  const int wv = tid >> 6;
  const int wg = blockIdx.x;
  const int j0 = (wg & 7) * 128 + (wg >> 3) * 4;

  // ---- stage W_ih slice (16 rows x 512) hi/lo bf16, XOR-swizzled ----
  for (int idx = tid; idx < 16 * 64; idx += 256) {
    int c = idx >> 6, kc8 = idx & 63;
    int grow = (c >> 2) * Hh + j0 + (c & 3);
    const float* src = W_ih + (long long)grow * Ee + kc8 * 8;
    int us = (c * 512 + kc8 * 8) ^ ((c & 7) << 3);
#pragma unroll
    for (int j = 0; j < 8; j++) {
      float f = src[j];
      unsigned short h = f2bf(f);
      sWih_hi[us + j] = h;
      sWih_lo[us + j] = f2bf(f - bf2f(h));
    }
  }
  // ---- stage W_hh slice (16 rows x 1024) ----
  for (int idx = tid; idx < 16 * 128; idx += 256) {
    int c = idx >> 7, kc8 = idx & 127;
    int grow = (c >> 2) * Hh + j0 + (c & 3);
    const float* src = W_hh + (long long)grow * Hh + kc8 * 8;
    int us = (c * 1024 + kc8 * 8) ^ ((c & 7) << 3);
#pragma unroll
    for (int j = 0; j < 8; j++) {
      float f = src[j];
      unsigned short h = f2bf(f);
      sWhh_hi[us + j] = h;
      sWhh_lo[us + j] = f2bf(f - bf2f(h));
    }
  }
  if (tid < 16) {
    int grow = (tid >> 2) * Hh + j0 + (tid & 3);
    sBias[tid] = b_ih[grow] + b_hh[grow];
  }
  if (tid < 128) sC[tid >> 2][tid & 3] = 0.f;
  __syncthreads();

  const int r16 = lane & 15;        // A-frag row (batch)
  const int kg = (lane >> 4) * 8;   // k-offset in 32-chunk
  const int col = lane & 15;        // B-frag col = gate-slice row
  const int xr = (col & 7) << 3;    // LDS swizzle

  const int grp = (wg >> 4) * 16;   // group counter (64B-padded stride)

  float h_last = 0.f, c_last = 0.f;

  for (int t = 0; t < Tt; t++) {
    f32x4 acc[2][3];
#pragma unroll
    for (int mt = 0; mt < 2; mt++)
#pragma unroll
      for (int cb = 0; cb < 3; cb++)
        acc[mt][cb] = (f32x4){0.f, 0.f, 0.f, 0.f};

    // ---- x_proj contribution (independent of h; overlaps barrier wait) ----
#pragma unroll
    for (int q = 0; q < 4; q++) {
      int kc = wv + q * 4;
      int bo = (col * 512 + kc * 32 + kg) ^ xr;
      bf16x8 bH = *(const bf16x8*)(sWih_hi + bo);
      bf16x8 bL = *(const bf16x8*)(sWih_lo + bo);
#pragma unroll
      for (int mt = 0; mt < 2; mt++) {
        int rb = mt * 16 + r16;
        int ai = (rb * Tt + t) * Ee + kc * 32 + kg;
        bf16x8 aH = *(const bf16x8*)(emb_hi + ai);
        bf16x8 aL = *(const bf16x8*)(emb_lo + ai);
        acc[mt][0] = __builtin_amdgcn_mfma_f32_16x16x32_bf16(aH, bH, acc[mt][0], 0, 0, 0);
        acc[mt][1] = __builtin_amdgcn_mfma_f32_16x16x32_bf16(aH, bL, acc[mt][1], 0, 0, 0);
        acc[mt][2] = __builtin_amdgcn_mfma_f32_16x16x32_bf16(aL, bH, acc[mt][2], 0, 0, 0);
      }
    }

    // ---- wait until h[t] is published: relaxed LLC spin (no fence after) ----
    if (tid == 0) {
      while (__hip_atomic_load(bar + 272, __ATOMIC_RELAXED,
                               __HIP_MEMORY_SCOPE_AGENT) < (unsigned)t)
        __builtin_amdgcn_s_sleep(1);
    }
    __syncthreads();

    // ---- recurrent contribution: K=1024 -> 32 k-chunks, sc1 h loads ----
    const unsigned short* hb = hbuf + (t & 1) * 65536;
#pragma unroll
    for (int q = 0; q < 8; q++) {
      int kc = wv + q * 4;
      int bo = (col * 1024 + kc * 32 + kg) ^ xr;
      bf16x8 bH = *(const bf16x8*)(sWhh_hi + bo);
      bf16x8 bL = *(const bf16x8*)(sWhh_lo + bo);
#pragma unroll
      for (int mt = 0; mt < 2; mt++) {
        int rb = mt * 16 + r16;
        int ai = rb * Hh + kc * 32 + kg;
        bf16x8 aH = llc_load16(hb + ai);
        bf16x8 aL = llc_load16(hb + 32768 + ai);
        acc[mt][0] = __builtin_amdgcn_mfma_f32_16x16x32_bf16(aH, bH, acc[mt][0], 0, 0, 0);
        acc[mt][1] = __builtin_amdgcn_mfma_f32_16x16x32_bf16(aH, bL, acc[mt][1], 0, 0, 0);
        acc[mt][2] = __builtin_amdgcn_mfma_f32_16x16x32_bf16(aL, bH, acc[mt][2], 0, 0, 0);
      }
    }

    // ---- cross-wave K-split reduction via LDS ----
#pragma unroll
    for (int mt = 0; mt < 2; mt++) {
      f32x4 tot = acc[mt][0] + acc[mt][1] + acc[mt][2];
#pragma unroll
      for (int r = 0; r < 4; r++)
        sAcc[wv][mt][(lane >> 4) * 4 + r][col] = tot[r];
    }
    __syncthreads();

    if (tid < 128) {
      int b = tid >> 2, du = tid & 3;
      int mt = b >> 4, rr = b & 15;
      float g0 = sBias[0 * 4 + du], g1 = sBias[1 * 4 + du];
      float g2 = sBias[2 * 4 + du], g3 = sBias[3 * 4 + du];
#pragma unroll
      for (int w = 0; w < 4; w++) {
        g0 += sAcc[w][mt][rr][0 * 4 + du];
        g1 += sAcc[w][mt][rr][1 * 4 + du];
        g2 += sAcc[w][mt][rr][2 * 4 + du];
        g3 += sAcc[w][mt][rr][3 * 4 + du];
      }
      float ig = sigmoidf_(g0);
      float fg = sigmoidf_(g1);
      float gg = tanh_fast(g2);
      float og = sigmoidf_(g3);
      float cn = fg * sC[b][du] + ig * gg;
      sC[b][du] = cn;
      float hn = og * tanh_fast(cn);
      h_last = hn; c_last = cn;
      int hj = j0 + du;
      out[((long long)b * Tt + t) * Hh + hj] = hn;   // plain (harness-only reader)

      // h broadcast: device-scope (LLC) u32 stores, hi/lo pairs via shfl
      unsigned short hh = f2bf(hn);
      unsigned short hl = f2bf(hn - bf2f(hh));
      unsigned pack = ((unsigned)hl << 16) | (unsigned)hh;
      unsigned other = __shfl_xor(pack, 1, 64);
      unsigned* nb32 = (unsigned*)(hbuf + ((t + 1) & 1) * 65536);
      int base = b * 1024 + j0;
      if ((du & 1) == 0) {
        unsigned w = (pack & 0xffffu) | ((other & 0xffffu) << 16);
        __hip_atomic_store(nb32 + ((base + du) >> 1), w,
                           __ATOMIC_RELAXED, __HIP_MEMORY_SCOPE_AGENT);
      } else {
        unsigned w = (other >> 16) | (pack & 0xffff0000u);
        __hip_atomic_store(nb32 + 16384 + ((base + du - 1) >> 1), w,
                           __ATOMIC_RELAXED, __HIP_MEMORY_SCOPE_AGENT);
      }
    }
    __syncthreads();   // per-wave vmcnt(0): sc1 stores at LLC before arrival

    // ---- arrive: 2-level monotonic barrier, all relaxed LLC atomics ----
    if (tid == 0) {
      unsigned old = __hip_atomic_fetch_add(bar + grp, 1u, __ATOMIC_RELAXED,
                                            __HIP_MEMORY_SCOPE_AGENT);
      if ((old & 15u) == 15u) {
        unsigned old2 = __hip_atomic_fetch_add(bar + 256, 1u, __ATOMIC_RELAXED,
                                               __HIP_MEMORY_SCOPE_AGENT);
        if ((old2 & 15u) == 15u) {
          __hip_atomic_store(bar + 272, (unsigned)(t + 1), __ATOMIC_RELAXED,
                             __HIP_MEMORY_SCOPE_AGENT);
        }
      }
    }
  }

  if (tid < 128) {
    int b = tid >> 2, du = tid & 3;
    int hj = j0 + du;
    out[16777216LL + b * Hh + hj] = h_last;           // state_h
    out[16777216LL + 32768 + b * Hh + hj] = c_last;   // state_c
  }
}

extern "C" void kernel_launch(void* const* d_in, const int* in_sizes, int n_in,
                              void* d_out, int out_size, void* d_ws, size_t ws_size,
                              hipStream_t stream) {
  const int* x      = (const int*)d_in[0];
  const float* emb  = (const float*)d_in[1];
  const float* W_ih = (const float*)d_in[2];
  const float* W_hh = (const float*)d_in[3];
  const float* b_ih = (const float*)d_in[4];
  const float* b_hh = (const float*)d_in[5];
  float* out = (float*)d_out;

  unsigned short* emb_hi = (unsigned short*)d_ws;      // 16 MB
  unsigned short* emb_lo = emb_hi + 8388608;           // 16 MB
  unsigned short* hbuf   = emb_lo + 8388608;           // 2 x (hi+lo) x 32 x 1024 = 256 KB
  unsigned*       bar    = (unsigned*)(hbuf + 131072); // barrier state (1152 B)

  hipLaunchKernelGGL(gather_kernel, dim3(2048), dim3(256), 0, stream,
                     x, emb, emb_hi, emb_lo, hbuf, bar);

  void* args[] = { (void*)&emb_hi, (void*)&emb_lo, (void*)&hbuf, (void*)&bar,
                   (void*)&W_ih, (void*)&W_hh, (void*)&b_ih, (void*)&b_hh,
                   (void*)&out };
  hipLaunchCooperativeKernel((void*)lstm_kernel, dim3(256), dim3(256), args, 0, stream);
}

// Round 5
// 4053.662 us; speedup vs baseline: 5.0853x; 1.4814x over previous
//
#include <hip/hip_runtime.h>

#define Bb 32
#define Tt 512
#define Ee 512
#define Hh 1024

typedef __attribute__((ext_vector_type(8))) short bf16x8;
typedef __attribute__((ext_vector_type(4))) float f32x4;
typedef unsigned long long u64;

__device__ __forceinline__ unsigned short f2bf(float f) {
  unsigned int u = __float_as_uint(f);
  u = (u + 0x7fffu + ((u >> 16) & 1u)) >> 16;
  return (unsigned short)u;
}
__device__ __forceinline__ float bf2f(unsigned short s) {
  return __uint_as_float(((unsigned int)s) << 16);
}
__device__ __forceinline__ float sigmoidf_(float x) {
  x = fminf(fmaxf(x, -30.f), 30.f);
  return 1.f / (1.f + __expf(-x));
}
__device__ __forceinline__ float tanh_fast(float x) {
  float xx = fminf(fmaxf(x, -15.f), 15.f);
  float e = __expf(2.f * xx);
  return (e - 1.f) / (e + 1.f);
}

// Device-scope (LLC) 16B read as two relaxed u64 atomic loads: bypasses
// stale L1/L2 — no fences needed anywhere in the step loop.
__device__ __forceinline__ bf16x8 llc_load16(const unsigned short* p) {
  union { u64 q[2]; bf16x8 v; } u;
  const u64* p64 = (const u64*)p;
  u.q[0] = __hip_atomic_load(p64 + 0, __ATOMIC_RELAXED, __HIP_MEMORY_SCOPE_AGENT);
  u.q[1] = __hip_atomic_load(p64 + 1, __ATOMIC_RELAXED, __HIP_MEMORY_SCOPE_AGENT);
  return u.v;
}

// K1: gather embedding rows -> bf16 hi/lo; zero h buffers and flag state.
__global__ void gather_kernel(const int* __restrict__ x,
                              const float* __restrict__ emb,
                              unsigned short* __restrict__ emb_hi,
                              unsigned short* __restrict__ emb_lo,
                              unsigned short* __restrict__ hbuf,
                              unsigned* __restrict__ bar) {
  long long gid = (long long)blockIdx.x * blockDim.x + threadIdx.x;
  long long stride = (long long)gridDim.x * blockDim.x;
  // hbuf: 2 slots x 32x1024 ushorts = 16384 ushort4
  for (long long i = gid; i < 16384; i += stride)
    ((ushort4*)hbuf)[i] = make_ushort4(0, 0, 0, 0);
  for (long long i = gid; i < 1024; i += stride)
    bar[i] = 0u;
  long long n4 = (long long)Bb * Tt * Ee / 4;
  for (long long i = gid; i < n4; i += stride) {
    long long bt = i >> 7;
    int e4 = (int)(i & 127);
    int row = x[bt];
    row = min(max(row, 0), 31999);
    float4 v = ((const float4*)(emb + (long long)row * Ee))[e4];
    ushort4 hv, lv;
    hv.x = f2bf(v.x); lv.x = f2bf(v.x - bf2f(hv.x));
    hv.y = f2bf(v.y); lv.y = f2bf(v.y - bf2f(hv.y));
    hv.z = f2bf(v.z); lv.z = f2bf(v.z - bf2f(hv.z));
    hv.w = f2bf(v.w); lv.w = f2bf(v.w - bf2f(hv.w));
    ((ushort4*)emb_hi)[i] = hv;
    ((ushort4*)emb_lo)[i] = lv;
  }
}

// K2: persistent LSTM. 256 WGs; WG owns units j0..j0+3, j0=(wg&7)*128+(wg>>3)*4.
// Sync = 32 per-K-group monotonic flag counters at LLC (64B-strided).
// Producer cell-waves: vmcnt(0) drain -> +1 on flag[g]; 16 contributions/step.
// Consumer waves: poll only their 8 groups (8 lanes, 1 gather/poll), then MFMA.
__global__ __launch_bounds__(256, 1)
void lstm_kernel(const unsigned short* __restrict__ emb_hi,
                 const unsigned short* __restrict__ emb_lo,
                 unsigned short* __restrict__ hbuf,
                 unsigned* __restrict__ bar,
                 const float* __restrict__ W_ih,
                 const float* __restrict__ W_hh,
                 const float* __restrict__ b_ih,
                 const float* __restrict__ b_hh,
                 float* __restrict__ out) {
  __shared__ unsigned short sWih_hi[16 * 512];
  __shared__ unsigned short sWih_lo[16 * 512];
  __shared__ unsigned short sWhh_hi[16 * 1024];
  __shared__ unsigned short sWhh_lo[16 * 1024];
  __shared__ float sAcc[2][4][2][16][17];   // [parity][wave][mt][row][col]
  __shared__ float sBias[16];
  __shared__ float sC[32][4];

  const int tid = threadIdx.x;
  const int lane = tid & 63;
  const int wv = tid >> 6;
  const int wg = blockIdx.x;
  const int j0 = (wg & 7) * 128 + (wg >> 3) * 4;
  const int gflag = (wg & 7) * 4 + (wg >> 6);   // = j0 >> 5

  // ---- stage W_ih slice (16 rows x 512) hi/lo bf16, XOR-swizzled ----
  for (int idx = tid; idx < 16 * 64; idx += 256) {
    int c = idx >> 6, kc8 = idx & 63;
    int grow = (c >> 2) * Hh + j0 + (c & 3);
    const float* src = W_ih + (long long)grow * Ee + kc8 * 8;
    int us = (c * 512 + kc8 * 8) ^ ((c & 7) << 3);
#pragma unroll
    for (int j = 0; j < 8; j++) {
      float f = src[j];
      unsigned short h = f2bf(f);
      sWih_hi[us + j] = h;
      sWih_lo[us + j] = f2bf(f - bf2f(h));
    }
  }
  // ---- stage W_hh slice (16 rows x 1024) ----
  for (int idx = tid; idx < 16 * 128; idx += 256) {
    int c = idx >> 7, kc8 = idx & 127;
    int grow = (c >> 2) * Hh + j0 + (c & 3);
    const float* src = W_hh + (long long)grow * Hh + kc8 * 8;
    int us = (c * 1024 + kc8 * 8) ^ ((c & 7) << 3);
#pragma unroll
    for (int j = 0; j < 8; j++) {
      float f = src[j];
      unsigned short h = f2bf(f);
      sWhh_hi[us + j] = h;
      sWhh_lo[us + j] = f2bf(f - bf2f(h));
    }
  }
  if (tid < 16) {
    int grow = (tid >> 2) * Hh + j0 + (tid & 3);
    sBias[tid] = b_ih[grow] + b_hh[grow];
  }
  if (tid < 128) sC[tid >> 2][tid & 3] = 0.f;
  __syncthreads();

  const int r16 = lane & 15;        // A-frag row (batch)
  const int kg = (lane >> 4) * 8;   // k-offset in 32-chunk
  const int col = lane & 15;        // B-frag col = gate-slice row
  const int xr = (col & 7) << 3;    // LDS swizzle

  // this wave's 8 flag pointers (one per lane 0..7, others duplicate)
  const unsigned* fp = bar + (unsigned)(wv + 4 * (lane & 7)) * 16;

  float h_last = 0.f, c_last = 0.f;

  for (int t = 0; t < Tt; t++) {
    f32x4 acc[2][3];
#pragma unroll
    for (int mt = 0; mt < 2; mt++)
#pragma unroll
      for (int cb = 0; cb < 3; cb++)
        acc[mt][cb] = (f32x4){0.f, 0.f, 0.f, 0.f};

    // ---- x_proj contribution (independent of h; overlaps flag wait) ----
#pragma unroll
    for (int q = 0; q < 4; q++) {
      int kc = wv + q * 4;
      int bo = (col * 512 + kc * 32 + kg) ^ xr;
      bf16x8 bH = *(const bf16x8*)(sWih_hi + bo);
      bf16x8 bL = *(const bf16x8*)(sWih_lo + bo);
#pragma unroll
      for (int mt = 0; mt < 2; mt++) {
        int rb = mt * 16 + r16;
        int ai = (rb * Tt + t) * Ee + kc * 32 + kg;
        bf16x8 aH = *(const bf16x8*)(emb_hi + ai);
        bf16x8 aL = *(const bf16x8*)(emb_lo + ai);
        acc[mt][0] = __builtin_amdgcn_mfma_f32_16x16x32_bf16(aH, bH, acc[mt][0], 0, 0, 0);
        acc[mt][1] = __builtin_amdgcn_mfma_f32_16x16x32_bf16(aH, bL, acc[mt][1], 0, 0, 0);
        acc[mt][2] = __builtin_amdgcn_mfma_f32_16x16x32_bf16(aL, bH, acc[mt][2], 0, 0, 0);
      }
    }

    // ---- per-wave wait: this wave's 8 K-groups published for step t ----
    {
      unsigned target = 16u * (unsigned)t;
      while (__any(__hip_atomic_load(fp, __ATOMIC_RELAXED,
                                     __HIP_MEMORY_SCOPE_AGENT) < target))
        __builtin_amdgcn_s_sleep(2);
    }

    // ---- recurrent contribution: K=1024 -> 8 chunks/wave, sc1 h loads ----
    const unsigned short* hb = hbuf + (t & 1) * 32768;
#pragma unroll
    for (int q = 0; q < 8; q++) {
      int kc = wv + q * 4;
      int bo = (col * 1024 + kc * 32 + kg) ^ xr;
      bf16x8 bH = *(const bf16x8*)(sWhh_hi + bo);
      bf16x8 bL = *(const bf16x8*)(sWhh_lo + bo);
#pragma unroll
      for (int mt = 0; mt < 2; mt++) {
        int rb = mt * 16 + r16;
        bf16x8 aH = llc_load16(hb + rb * Hh + kc * 32 + kg);
        acc[mt][0] = __builtin_amdgcn_mfma_f32_16x16x32_bf16(aH, bH, acc[mt][0], 0, 0, 0);
        acc[mt][1] = __builtin_amdgcn_mfma_f32_16x16x32_bf16(aH, bL, acc[mt][1], 0, 0, 0);
      }
    }

    // ---- cross-wave K-split reduction via LDS (parity-double-buffered) ----
#pragma unroll
    for (int mt = 0; mt < 2; mt++) {
      f32x4 tot = acc[mt][0] + acc[mt][1] + acc[mt][2];
#pragma unroll
      for (int r = 0; r < 4; r++)
        sAcc[t & 1][wv][mt][(lane >> 4) * 4 + r][col] = tot[r];
    }
    __syncthreads();

    if (tid < 128) {
      int b = tid >> 2, du = tid & 3;
      int mt = b >> 4, rr = b & 15;
      float g0 = sBias[0 * 4 + du], g1 = sBias[1 * 4 + du];
      float g2 = sBias[2 * 4 + du], g3 = sBias[3 * 4 + du];
#pragma unroll
      for (int w = 0; w < 4; w++) {
        g0 += sAcc[t & 1][w][mt][rr][0 * 4 + du];
        g1 += sAcc[t & 1][w][mt][rr][1 * 4 + du];
        g2 += sAcc[t & 1][w][mt][rr][2 * 4 + du];
        g3 += sAcc[t & 1][w][mt][rr][3 * 4 + du];
      }
      float ig = sigmoidf_(g0);
      float fg = sigmoidf_(g1);
      float gg = tanh_fast(g2);
      float og = sigmoidf_(g3);
      float cn = fg * sC[b][du] + ig * gg;
      sC[b][du] = cn;
      float hn = og * tanh_fast(cn);
      h_last = hn; c_last = cn;

      // h broadcast first (single bf16), then flag, then out store
      unsigned pack = (unsigned)f2bf(hn);
      unsigned other = __shfl_xor(pack, 1, 64);
      unsigned* nb32 = (unsigned*)(hbuf + ((t + 1) & 1) * 32768);
      if ((du & 1) == 0) {
        unsigned w = (pack & 0xffffu) | (other << 16);
        __hip_atomic_store(nb32 + ((b * 1024 + j0 + du) >> 1), w,
                           __ATOMIC_RELAXED, __HIP_MEMORY_SCOPE_AGENT);
      }
      // wave-local drain of the sc1 stores, then one add per cell wave
      asm volatile("s_waitcnt vmcnt(0)" ::: "memory");
      if ((tid & 63) == 0)
        __hip_atomic_fetch_add(bar + gflag * 16, 1u, __ATOMIC_RELAXED,
                               __HIP_MEMORY_SCOPE_AGENT);
      out[((long long)b * Tt + t) * Hh + j0 + du] = hn;
    }
    // no tail barrier: sAcc is parity-buffered; hbuf 2-slot safety holds
  }

  if (tid < 128) {
    int b = tid >> 2, du = tid & 3;
    int hj = j0 + du;
    out[16777216LL + b * Hh + hj] = h_last;           // state_h
    out[16777216LL + 32768 + b * Hh + hj] = c_last;   // state_c
  }
}

extern "C" void kernel_launch(void* const* d_in, const int* in_sizes, int n_in,
                              void* d_out, int out_size, void* d_ws, size_t ws_size,
                              hipStream_t stream) {
  const int* x      = (const int*)d_in[0];
  const float* emb  = (const float*)d_in[1];
  const float* W_ih = (const float*)d_in[2];
  const float* W_hh = (const float*)d_in[3];
  const float* b_ih = (const float*)d_in[4];
  const float* b_hh = (const float*)d_in[5];
  float* out = (float*)d_out;

  unsigned short* emb_hi = (unsigned short*)d_ws;      // 16 MB
  unsigned short* emb_lo = emb_hi + 8388608;           // 16 MB
  unsigned short* hbuf   = emb_lo + 8388608;           // 2 x 32x1024 ushort = 128 KB
  unsigned*       bar    = (unsigned*)(hbuf + 65536);  // 32 flags @64B stride

  hipLaunchKernelGGL(gather_kernel, dim3(2048), dim3(256), 0, stream,
                     x, emb, emb_hi, emb_lo, hbuf, bar);

  void* args[] = { (void*)&emb_hi, (void*)&emb_lo, (void*)&hbuf, (void*)&bar,
                   (void*)&W_ih, (void*)&W_hh, (void*)&b_ih, (void*)&b_hh,
                   (void*)&out };
  hipLaunchCooperativeKernel((void*)lstm_kernel, dim3(256), dim3(256), args, 0, stream);
}